// Round 19
// baseline (254.495 us; speedup 1.0000x reference)
//
#include <hip/hip_runtime.h>
#include <hip/hip_bf16.h>
#include <stdint.h>

typedef __bf16 bf16x8 __attribute__((ext_vector_type(8)));
typedef float f32x4 __attribute__((ext_vector_type(4)));
typedef unsigned short u16;
typedef u16 u16x8 __attribute__((ext_vector_type(8)));

__device__ __forceinline__ float bf2f(u16 u) {
  union { uint32_t i; float f; } v; v.i = uint32_t(u) << 16; return v.f;
}
__device__ __forceinline__ u16 f2bf(float f) {
  union { float f; uint32_t i; } v; v.f = f;
  uint32_t r = v.i + 0x7FFFu + ((v.i >> 16) & 1u);  // RNE
  return (u16)(r >> 16);
}
__device__ __forceinline__ uint32_t pack2(float a, float b) {
  union { __bf16 h[2]; uint32_t u; } v;
  v.h[0] = (__bf16)a; v.h[1] = (__bf16)b; return v.u;
}
// raw v_exp_f32: D = 2^S0
__device__ __forceinline__ float exp2x(float x) { return __builtin_amdgcn_exp2f(x); }
__device__ __forceinline__ float max3f(float a, float b, float c) {
  return fmaxf(fmaxf(a, b), c);
}

// global -> LDS direct (16B per lane; LDS dest is wave-uniform base + lane*16)
typedef __attribute__((address_space(1))) const uint32_t gas_u32;
typedef __attribute__((address_space(3))) uint32_t las_u32;
__device__ __forceinline__ void gload_lds16(const u16* g, u16* l) {
  __builtin_amdgcn_global_load_lds((gas_u32*)g, (las_u32*)l, 16, 0, 0);
}

#define QSCL 0.180336880111f   // 0.125 * log2(e): softmax in exp2 domain

// ---------------------------------------------------------------------------
// Merged f32 -> bf16 conversion, grid-stride over 2048 blocks (G11).
// ---------------------------------------------------------------------------
__global__ __launch_bounds__(256) void conv5(
    const float* __restrict__ x, const float* __restrict__ wq,
    const float* __restrict__ wk, const float* __restrict__ wv,
    const float* __restrict__ wo,
    u16* __restrict__ Xb, u16* __restrict__ Wqb,
    u16* __restrict__ Wkb, u16* __restrict__ Wvb, u16* __restrict__ Wob)
{
  const int stride = 2048 * 256;
  for (int t0 = blockIdx.x * 256 + threadIdx.x; t0 < 2359296; t0 += stride) {
    int t = t0;
    const float* src; u16* dst;
    if (t < 1048576)      { src = x;  dst = Xb; }
    else if (t < 1572864) { src = wq; dst = Wqb; t -= 1048576; }
    else if (t < 1703936) { src = wk; dst = Wkb; t -= 1572864; }
    else if (t < 1835008) { src = wv; dst = Wvb; t -= 1703936; }
    else                  { src = wo; dst = Wob; t -= 1835008; }
    const int i = t * 8;
    const float4 a = *reinterpret_cast<const float4*>(src + i);
    const float4 b = *reinterpret_cast<const float4*>(src + i + 4);
    u16x8 o;
    o[0] = f2bf(a.x); o[1] = f2bf(a.y); o[2] = f2bf(a.z); o[3] = f2bf(a.w);
    o[4] = f2bf(b.x); o[5] = f2bf(b.y); o[6] = f2bf(b.z); o[7] = f2bf(b.w);
    *reinterpret_cast<u16x8*>(dst + i) = o;
  }
}

// ---------------------------------------------------------------------------
// GEMM core, BK=64, DOUBLE-BUFFERED (R14-proven).
// ---------------------------------------------------------------------------
__device__ __forceinline__ void gemm_core_db(
    const u16* __restrict__ A, const u16* __restrict__ Bw,
    int row0, int col0, int K,
    u16* As0, u16* As1, u16* Bs0, u16* Bs1, f32x4 acc[4][4])
{
  const int tid = threadIdx.x, wv = tid >> 6, lane = tid & 63;
  const int l15 = lane & 15, lhi = lane >> 4;
  const int wr = (wv >> 1) * 64, wc = (wv & 1) * 64;

  int srow[4], scol[4], ldso[4];
#pragma unroll
  for (int sh = 0; sh < 4; ++sh) {
    const int idx = sh * 256 + tid;
    srow[sh] = idx >> 3;
    scol[sh] = ((idx & 7) ^ (srow[sh] & 7)) * 8;
    ldso[sh] = (sh * 256 + wv * 64) * 8;
  }
  const u16* const gA = A + (size_t)row0 * K;
  const u16* const gB = Bw + (size_t)col0 * K;

#pragma unroll
  for (int sh = 0; sh < 4; ++sh)
    gload_lds16(gA + (size_t)srow[sh] * K + scol[sh], As0 + ldso[sh]);
#pragma unroll
  for (int sh = 0; sh < 4; ++sh)
    gload_lds16(gB + (size_t)srow[sh] * K + scol[sh], Bs0 + ldso[sh]);
  __syncthreads();

  for (int k0 = 0; k0 < K; k0 += 64) {
    u16* const Ac = (k0 & 64) ? As1 : As0;
    u16* const Bc = (k0 & 64) ? Bs1 : Bs0;
    if (k0 + 64 < K) {
      u16* const An = (k0 & 64) ? As0 : As1;
      u16* const Bn = (k0 & 64) ? Bs0 : Bs1;
#pragma unroll
      for (int sh = 0; sh < 4; ++sh)
        gload_lds16(gA + (size_t)srow[sh] * K + k0 + 64 + scol[sh], An + ldso[sh]);
#pragma unroll
      for (int sh = 0; sh < 4; ++sh)
        gload_lds16(gB + (size_t)srow[sh] * K + k0 + 64 + scol[sh], Bn + ldso[sh]);
    }
#pragma unroll
    for (int kc = 0; kc < 2; ++kc) {
      bf16x8 af[4], bfv[4];
#pragma unroll
      for (int i = 0; i < 4; ++i) {
        const int ra = wr + i * 16 + l15;
        af[i] = *reinterpret_cast<const bf16x8*>(
            reinterpret_cast<const char*>(Ac) +
            ((ra * 128 + kc * 64 + lhi * 16) ^ ((ra & 7) << 4)));
        const int rb = wc + i * 16 + l15;
        bfv[i] = *reinterpret_cast<const bf16x8*>(
            reinterpret_cast<const char*>(Bc) +
            ((rb * 128 + kc * 64 + lhi * 16) ^ ((rb & 7) << 4)));
      }
#pragma unroll
      for (int mi = 0; mi < 4; ++mi)
#pragma unroll
        for (int ni = 0; ni < 4; ++ni)
          acc[mi][ni] = __builtin_amdgcn_mfma_f32_16x16x32_bf16(af[mi], bfv[ni], acc[mi][ni], 0, 0, 0);
    }
    __syncthreads();
  }
}

// ---------------------------------------------------------------------------
// Fused Q+K+V projection, one launch, 768 blocks.
// ---------------------------------------------------------------------------
__global__ __launch_bounds__(256) void gemm_qkv(
    const u16* __restrict__ A, const u16* __restrict__ Wq,
    const u16* __restrict__ Wk, const u16* __restrict__ Wv,
    u16* __restrict__ Qout, u16* __restrict__ Kout, u16* __restrict__ VTout,
    const float* __restrict__ cosb, const float* __restrict__ sinb)
{
  __shared__ u16 As[2][128 * 64];
  __shared__ u16 Bs[2][128 * 64];
  int lin = blockIdx.x;
  lin = (lin & 7) * 96 + (lin >> 3);          // XCD swizzle, nwg=768
  const int lane = threadIdx.x & 63, wvi = threadIdx.x >> 6;
  const int wr = (wvi >> 1) * 64, wc = (wvi & 1) * 64;
  const int l15 = lane & 15;
  f32x4 acc[4][4] = {};

  if (lin < 512) {
    const int row0 = (lin >> 4) * 128, col0 = (lin & 15) * 128;
    gemm_core_db(A, Wq, row0, col0, 2048, As[0], As[1], Bs[0], Bs[1], acc);
#pragma unroll
    for (int mi = 0; mi < 4; ++mi) {
      const int r0 = row0 + wr + mi * 16 + ((lane >> 4) << 2);
#pragma unroll
      for (int ni = 0; ni < 4; ++ni) {
        const int c = col0 + wc + ni * 16 + l15;
#pragma unroll
        for (int r = 0; r < 4; ++r) {
          const int s = (r0 + r) & 2047;
          const int jj = (c & 63) >> 1;
          const float cvv = cosb[s * 32 + jj], svv = sinb[s * 32 + jj];
          const float val = acc[mi][ni][r];
          const float part = __shfl_xor(val, 1);
          const float sgn = (c & 1) ? svv : -svv;
          Qout[(size_t)(r0 + r) * 2048 + c] = f2bf((val * cvv + part * sgn) * QSCL);
        }
      }
    }
  } else {
    const int t = lin - 512;
    const int bx = t & 7, by = t >> 3;
    const bool isV = bx >= 4;
    const int col0 = (bx & 3) * 128;
    const int row0 = by * 128;
    gemm_core_db(A, isV ? Wv : Wk, row0, col0, 2048, As[0], As[1], Bs[0], Bs[1], acc);
#pragma unroll
    for (int mi = 0; mi < 4; ++mi) {
      const int r0 = row0 + wr + mi * 16 + ((lane >> 4) << 2);
#pragma unroll
      for (int ni = 0; ni < 4; ++ni) {
        const int c = col0 + wc + ni * 16 + l15;
#pragma unroll
        for (int r = 0; r < 4; ++r) {
          if (isV) {
            VTout[(size_t)c * 4096 + (r0 + r)] = f2bf(acc[mi][ni][r]);
          } else {
            const int s = (r0 + r) & 2047;
            const int jj = (c & 63) >> 1;
            const float cvv = cosb[s * 32 + jj], svv = sinb[s * 32 + jj];
            const float val = acc[mi][ni][r];
            const float part = __shfl_xor(val, 1);
            const float sgn = (c & 1) ? svv : -svv;
            Kout[(size_t)(r0 + r) * 512 + c] = f2bf(val * cvv + part * sgn);
          }
        }
      }
    }
  }
}

// Output projection -> f32 d_out
__global__ __launch_bounds__(256) void gemm_out(
    const u16* __restrict__ A, const u16* __restrict__ Bw, float* __restrict__ C,
    int N, int K)
{
  __shared__ u16 As[2][128 * 64];
  __shared__ u16 Bs[2][128 * 64];
  const int nwg = gridDim.x * gridDim.y;
  int lin = blockIdx.y * gridDim.x + blockIdx.x;
  lin = (lin & 7) * (nwg >> 3) + (lin >> 3);
  const int row0 = (lin / gridDim.x) * 128, col0 = (lin % gridDim.x) * 128;
  f32x4 acc[4][4] = {};
  gemm_core_db(A, Bw, row0, col0, K, As[0], As[1], Bs[0], Bs[1], acc);

  const int lane = threadIdx.x & 63, wvi = threadIdx.x >> 6;
  const int wr = (wvi >> 1) * 64, wc = (wvi & 1) * 64;
  const int l15 = lane & 15;
#pragma unroll
  for (int mi = 0; mi < 4; ++mi) {
    const int r0 = row0 + wr + mi * 16 + ((lane >> 4) << 2);
#pragma unroll
    for (int ni = 0; ni < 4; ++ni) {
      const int c = col0 + wc + ni * 16 + l15;
#pragma unroll
      for (int r = 0; r < 4; ++r)
        C[(size_t)(r0 + r) * N + c] = acc[mi][ni][r];
    }
  }
}

// ---------------------------------------------------------------------------
// Attention LDS helper: tiles [rows][64] bf16 (128B rows), byte ^= ((row&7)<<4)
// ---------------------------------------------------------------------------
__device__ __forceinline__ bf16x8 lds_read8(const u16* base, int row, int col) {
  const int byte = (row * 128 + col * 2) ^ ((row & 7) << 4);
  return *reinterpret_cast<const bf16x8*>(reinterpret_cast<const char*>(base) + byte);
}

// ---------------------------------------------------------------------------
// One q-set (16 rows) update vs a 64-kv tile. Swapped QK^T (lane l15 = q-row),
// exp2-domain, shfl-free defer-max, row-sum via ones-operand MFMA.
// P relayout IN-REGISTER via bpermute (no LDS round-trip):
//   source lane (q, h) holds p[f][r] = P[kv=16f+4h+r][q], packed as
//   c[f][j] = pack2(p[f][2j], p[f][2j+1]).
//   PV A-frag: lane (q, h') word w of kc-chunk = c[2kc + (h'>>1)][w&1]
//   from lane (q, 2*(h'&1) + (w>>1)). 16 independent shfls + 8 selects.
// ---------------------------------------------------------------------------
__device__ __forceinline__ void attn_set(
    const u16* __restrict__ Ks, const u16* __restrict__ Vt,
    const bf16x8 qf[2], const bf16x8 ones, int t0, int qbase, int l15, int lhi,
    float& mrun, f32x4& lrun, f32x4 oacc[4])
{
  f32x4 s[4] = {};
  __builtin_amdgcn_s_setprio(1);
#pragma unroll
  for (int kc = 0; kc < 2; ++kc)
#pragma unroll
    for (int f = 0; f < 4; ++f) {
      const bf16x8 kf = lds_read8(Ks, f * 16 + l15, kc * 32 + lhi * 8);
      s[f] = __builtin_amdgcn_mfma_f32_16x16x32_bf16(kf, qf[kc], s[f], 0, 0, 0);
    }
  __builtin_amdgcn_s_setprio(0);
  float v[4][4];
#pragma unroll
  for (int f = 0; f < 4; ++f)
#pragma unroll
    for (int r = 0; r < 4; ++r) v[f][r] = s[f][r];
  if (t0 + 63 > qbase) {   // diagonal tile only (wave-uniform branch)
#pragma unroll
    for (int f = 0; f < 4; ++f)
#pragma unroll
      for (int r = 0; r < 4; ++r)
        if (t0 + f * 16 + lhi * 4 + r > qbase + l15) v[f][r] = -1e30f;
  }
  // fast path: exp first, in-lane max, scalar __all — no cross-lane shfl
  float p[4][4];
#pragma unroll
  for (int f = 0; f < 4; ++f)
#pragma unroll
    for (int r = 0; r < 4; ++r) p[f][r] = exp2x(v[f][r] - mrun);
  float m1 = max3f(p[0][0], p[0][1], p[0][2]);
  float m2 = max3f(p[0][3], p[1][0], p[1][1]);
  float m3 = max3f(p[1][2], p[1][3], p[2][0]);
  float m4 = max3f(p[2][1], p[2][2], p[2][3]);
  float m5 = max3f(p[3][0], p[3][1], p[3][2]);
  const float pmax = fmaxf(max3f(m1, m2, m3), max3f(m4, m5, p[3][3]));
  if (!__all(pmax <= 256.f)) {
    float t1 = max3f(v[0][0], v[0][1], v[0][2]);
    float t2 = max3f(v[0][3], v[1][0], v[1][1]);
    float t3 = max3f(v[1][2], v[1][3], v[2][0]);
    float t4 = max3f(v[2][1], v[2][2], v[2][3]);
    float t5 = max3f(v[3][0], v[3][1], v[3][2]);
    float mx = fmaxf(max3f(t1, t2, t3), max3f(t4, t5, v[3][3]));
    mx = fmaxf(mx, __shfl_xor(mx, 16));
    mx = fmaxf(mx, __shfl_xor(mx, 32));
    const float newm = fmaxf(mrun, mx);
    const float fac = exp2x(mrun - newm);
    mrun = newm;
    float facq[4];
#pragma unroll
    for (int r = 0; r < 4; ++r) facq[r] = __shfl(fac, lhi * 4 + r);
#pragma unroll
    for (int r = 0; r < 4; ++r) lrun[r] *= facq[r];
#pragma unroll
    for (int nf = 0; nf < 4; ++nf)
#pragma unroll
      for (int r = 0; r < 4; ++r) oacc[nf][r] *= facq[r];
#pragma unroll
    for (int f = 0; f < 4; ++f)
#pragma unroll
      for (int r = 0; r < 4; ++r) p[f][r] = exp2x(v[f][r] - mrun);
  }
  // pack P into u32 pairs
  uint32_t c[4][2];
#pragma unroll
  for (int f = 0; f < 4; ++f) {
    c[f][0] = pack2(p[f][0], p[f][1]);
    c[f][1] = pack2(p[f][2], p[f][3]);
  }
  const int sl0 = l15 + ((lhi & 1) << 5);   // lane (q, 2*(h'&1))
  const int sl1 = sl0 + 16;                 // lane (q, 2*(h'&1)+1)
  const bool hi = (lhi >> 1) != 0;          // select f = 2kc+1 half
  __builtin_amdgcn_s_setprio(1);
#pragma unroll
  for (int kc = 0; kc < 2; ++kc) {
    const uint32_t a0 = __shfl((int)c[2 * kc][0],     sl0);
    const uint32_t b0 = __shfl((int)c[2 * kc + 1][0], sl0);
    const uint32_t a1 = __shfl((int)c[2 * kc][1],     sl0);
    const uint32_t b1 = __shfl((int)c[2 * kc + 1][1], sl0);
    const uint32_t a2 = __shfl((int)c[2 * kc][0],     sl1);
    const uint32_t b2 = __shfl((int)c[2 * kc + 1][0], sl1);
    const uint32_t a3 = __shfl((int)c[2 * kc][1],     sl1);
    const uint32_t b3 = __shfl((int)c[2 * kc + 1][1], sl1);
    union { uint32_t w[4]; bf16x8 v; } pa;
    pa.w[0] = hi ? b0 : a0;
    pa.w[1] = hi ? b1 : a1;
    pa.w[2] = hi ? b2 : a2;
    pa.w[3] = hi ? b3 : a3;
    lrun = __builtin_amdgcn_mfma_f32_16x16x32_bf16(pa.v, ones, lrun, 0, 0, 0);
#pragma unroll
    for (int nf = 0; nf < 4; ++nf) {
      const bf16x8 vf = lds_read8(Vt, nf * 16 + l15, kc * 32 + lhi * 8);
      oacc[nf] = __builtin_amdgcn_mfma_f32_16x16x32_bf16(pa.v, vf, oacc[nf], 0, 0, 0);
    }
  }
  __builtin_amdgcn_s_setprio(0);
}

__device__ __forceinline__ void attn_store(
    u16* __restrict__ O, const size_t qoff, const int h, const int qbase,
    const int l15, const int lhi, const f32x4 lrun, const f32x4 oacc[4])
{
  float linv[4];
#pragma unroll
  for (int r = 0; r < 4; ++r) linv[r] = 1.f / lrun[r];
#pragma unroll
  for (int nf = 0; nf < 4; ++nf)
#pragma unroll
    for (int r = 0; r < 4; ++r)
      O[qoff + (size_t)(qbase + lhi * 4 + r) * 2048 + h * 64 + nf * 16 + l15] =
          f2bf(oacc[nf][r] * linv[r]);
}

// ---------------------------------------------------------------------------
// Causal flash attention, GQA. Grid (16, 32, 2); block 256 = 4 waves.
// Balanced pairing: block j handles q-tile j AND q-tile 31-j (33 updates).
// K/V^T double-buffered via global_load_lds; P relayout fully in-register.
// LDS 32 KB.
// ---------------------------------------------------------------------------
__global__ __launch_bounds__(256) void attn_kernel(
    const u16* __restrict__ Q, const u16* __restrict__ K,
    const u16* __restrict__ VT, u16* __restrict__ O)
{
  __shared__ u16 Ks[2][64 * 64];
  __shared__ u16 Vt[2][64 * 64];

  const int j  = blockIdx.x;            // 0..15
  const int h  = blockIdx.y;
  const int b  = blockIdx.z;
  const int kh = h >> 2;
  const int tid = threadIdx.x, wv = tid >> 6, lane = tid & 63;
  const int l15 = lane & 15, lhi = lane >> 4;
  const size_t qoff = (size_t)b * 2048 * 2048;
  const size_t koff = (size_t)b * 2048 * 512;

  const int qAb = j * 64 + wv * 16;
  const int qBb = (31 - j) * 64 + wv * 16;

  const int idx0 = tid, idx1 = tid + 256;
  const int r0 = idx0 >> 3, u0 = (idx0 & 7) ^ (r0 & 7);
  const int r1 = idx1 >> 3, u1 = (idx1 & 7) ^ (r1 & 7);
  const u16* const kg0 = K + koff + (size_t)r0 * 512 + kh * 64 + u0 * 8;
  const u16* const kg1 = K + koff + (size_t)r1 * 512 + kh * 64 + u1 * 8;
  const u16* const vg0 = VT + (size_t)(kh * 64 + r0) * 4096 + b * 2048 + u0 * 8;
  const u16* const vg1 = VT + (size_t)(kh * 64 + r1) * 4096 + b * 2048 + u1 * 8;
  const int ld0 = wv * 512;
  const int ld1 = 2048 + wv * 512;

  bf16x8 qfA[2], qfB[2];
#pragma unroll
  for (int kc = 0; kc < 2; ++kc) {
    qfA[kc] = *reinterpret_cast<const bf16x8*>(
        Q + qoff + (size_t)(qAb + l15) * 2048 + h * 64 + kc * 32 + lhi * 8);
    qfB[kc] = *reinterpret_cast<const bf16x8*>(
        Q + qoff + (size_t)(qBb + l15) * 2048 + h * 64 + kc * 32 + lhi * 8);
  }
  bf16x8 ones;
#pragma unroll
  for (int i = 0; i < 8; ++i) ones[i] = (__bf16)1.0f;

  float mA = -1e30f, mB = -1e30f;
  f32x4 lA = {}, lB = {};
  f32x4 oA[4] = {}, oB[4] = {};

  const int tlast = 31 - j;

  gload_lds16(kg0, &Ks[0][ld0]);
  gload_lds16(kg1, &Ks[0][ld1]);
  gload_lds16(vg0, &Vt[0][ld0]);
  gload_lds16(vg1, &Vt[0][ld1]);
  __syncthreads();

  int cur = 0;
  for (int t = 0; t <= tlast; ++t) {
    const int t0 = t * 64;
    if (t < tlast) {
      const int n0 = t0 + 64;
      const int nb = cur ^ 1;
      gload_lds16(kg0 + (size_t)n0 * 512, &Ks[nb][ld0]);
      gload_lds16(kg1 + (size_t)n0 * 512, &Ks[nb][ld1]);
      gload_lds16(vg0 + n0, &Vt[nb][ld0]);
      gload_lds16(vg1 + n0, &Vt[nb][ld1]);
    }

    if (t <= j)
      attn_set(Ks[cur], Vt[cur], qfA, ones, t0, qAb, l15, lhi, mA, lA, oA);
    attn_set(Ks[cur], Vt[cur], qfB, ones, t0, qBb, l15, lhi, mB, lB, oB);

    __syncthreads();
    cur ^= 1;
  }

  attn_store(O, qoff, h, qAb, l15, lhi, lA, oA);
  attn_store(O, qoff, h, qBb, l15, lhi, lB, oB);
}

// ---------------------------------------------------------------------------
extern "C" void kernel_launch(void* const* d_in, const int* in_sizes, int n_in,
                              void* d_out, int out_size, void* d_ws, size_t ws_size,
                              hipStream_t stream)
{
  const float* x  = (const float*)d_in[0];
  const float* fc = (const float*)d_in[1];
  const float* fs = (const float*)d_in[2];
  // d_in[3] = mask (causal; analytic)
  const float* wq = (const float*)d_in[4];
  const float* wk = (const float*)d_in[5];
  const float* wv = (const float*)d_in[6];
  const float* wo = (const float*)d_in[7];
  float* out = (float*)d_out;

  u16* Xb  = (u16*)d_ws;                          // 4096 x 2048
  u16* Wqb = Xb  + (size_t)4096 * 2048;           // 2048 x 2048
  u16* Wkb = Wqb + (size_t)2048 * 2048;           // 512 x 2048
  u16* Wvb = Wkb + (size_t)512 * 2048;            // 512 x 2048
  u16* Qws = Wvb + (size_t)512 * 2048;            // 4096 x 2048
  u16* Kws = Qws + (size_t)4096 * 2048;           // 4096 x 512
  u16* VTws = Kws + (size_t)4096 * 512;           // 512 x 4096  (V transposed)
  u16* Wob = VTws + (size_t)512 * 4096;           // 2048 x 2048
  u16* Ows = Xb;                                  // alias: x dead after QKV

  dim3 blk(256);
  conv5<<<dim3(2048), blk, 0, stream>>>(
      x, wq, wk, wv, wo, Xb, Wqb, Wkb, Wvb, Wob);
  // Fused Q+K+V projections (Q/K with RoPE; V transposed)
  gemm_qkv<<<dim3(768), blk, 0, stream>>>(Xb, Wqb, Wkb, Wvb, Qws, Kws, VTws, fc, fs);
  // Flash attention
  attn_kernel<<<dim3(16, 32, 2), blk, 0, stream>>>(Qws, Kws, VTws, Ows);
  // Output projection -> f32
  gemm_out<<<dim3(16, 32), blk, 0, stream>>>(Ows, Wob, out, 2048, 2048);
}

// Round 20
// 239.603 us; speedup vs baseline: 1.0622x; 1.0622x over previous
//
#include <hip/hip_runtime.h>
#include <hip/hip_bf16.h>
#include <stdint.h>

typedef __bf16 bf16x8 __attribute__((ext_vector_type(8)));
typedef float f32x4 __attribute__((ext_vector_type(4)));
typedef unsigned short u16;
typedef u16 u16x8 __attribute__((ext_vector_type(8)));

__device__ __forceinline__ float bf2f(u16 u) {
  union { uint32_t i; float f; } v; v.i = uint32_t(u) << 16; return v.f;
}
__device__ __forceinline__ u16 f2bf(float f) {
  union { float f; uint32_t i; } v; v.f = f;
  uint32_t r = v.i + 0x7FFFu + ((v.i >> 16) & 1u);  // RNE
  return (u16)(r >> 16);
}
__device__ __forceinline__ uint32_t pack2(float a, float b) {
  union { __bf16 h[2]; uint32_t u; } v;
  v.h[0] = (__bf16)a; v.h[1] = (__bf16)b; return v.u;
}
// raw v_exp_f32: D = 2^S0
__device__ __forceinline__ float exp2x(float x) { return __builtin_amdgcn_exp2f(x); }
__device__ __forceinline__ float max3f(float a, float b, float c) {
  return fmaxf(fmaxf(a, b), c);
}

// global -> LDS direct (16B per lane; LDS dest is wave-uniform base + lane*16)
typedef __attribute__((address_space(1))) const uint32_t gas_u32;
typedef __attribute__((address_space(3))) uint32_t las_u32;
__device__ __forceinline__ void gload_lds16(const u16* g, u16* l) {
  __builtin_amdgcn_global_load_lds((gas_u32*)g, (las_u32*)l, 16, 0, 0);
}

#define QSCL 0.180336880111f   // 0.125 * log2(e): softmax in exp2 domain

// ---------------------------------------------------------------------------
// Merged f32 -> bf16 conversion for x, wq, wk, wv, wo (one launch)
// ---------------------------------------------------------------------------
__global__ __launch_bounds__(256) void conv5(
    const float* __restrict__ x, const float* __restrict__ wq,
    const float* __restrict__ wk, const float* __restrict__ wv,
    const float* __restrict__ wo,
    u16* __restrict__ Xb, u16* __restrict__ Wqb,
    u16* __restrict__ Wkb, u16* __restrict__ Wvb, u16* __restrict__ Wob)
{
  int t = blockIdx.x * 256 + threadIdx.x;
  const float* src; u16* dst;
  if (t < 1048576)      { src = x;  dst = Xb; }
  else if (t < 1572864) { src = wq; dst = Wqb; t -= 1048576; }
  else if (t < 1703936) { src = wk; dst = Wkb; t -= 1572864; }
  else if (t < 1835008) { src = wv; dst = Wvb; t -= 1703936; }
  else                  { src = wo; dst = Wob; t -= 1835008; }
  const int i = t * 8;
  const float4 a = *reinterpret_cast<const float4*>(src + i);
  const float4 b = *reinterpret_cast<const float4*>(src + i + 4);
  u16x8 o;
  o[0] = f2bf(a.x); o[1] = f2bf(a.y); o[2] = f2bf(a.z); o[3] = f2bf(a.w);
  o[4] = f2bf(b.x); o[5] = f2bf(b.y); o[6] = f2bf(b.z); o[7] = f2bf(b.w);
  *reinterpret_cast<u16x8*>(dst + i) = o;
}

// ---------------------------------------------------------------------------
// GEMM core, BK=64, DOUBLE-BUFFERED (R14-proven): prologue stages tile 0;
// each iter issues next tile's global_load_lds into buf^1 FIRST, computes
// current, one __syncthreads, flip. LDS 64 KB.
// ---------------------------------------------------------------------------
__device__ __forceinline__ void gemm_core_db(
    const u16* __restrict__ A, const u16* __restrict__ Bw,
    int row0, int col0, int K,
    u16* As0, u16* As1, u16* Bs0, u16* Bs1, f32x4 acc[4][4])
{
  const int tid = threadIdx.x, wv = tid >> 6, lane = tid & 63;
  const int l15 = lane & 15, lhi = lane >> 4;
  const int wr = (wv >> 1) * 64, wc = (wv & 1) * 64;

  int srow[4], scol[4], ldso[4];
#pragma unroll
  for (int sh = 0; sh < 4; ++sh) {
    const int idx = sh * 256 + tid;
    srow[sh] = idx >> 3;
    scol[sh] = ((idx & 7) ^ (srow[sh] & 7)) * 8;
    ldso[sh] = (sh * 256 + wv * 64) * 8;
  }
  const u16* const gA = A + (size_t)row0 * K;
  const u16* const gB = Bw + (size_t)col0 * K;

#pragma unroll
  for (int sh = 0; sh < 4; ++sh)
    gload_lds16(gA + (size_t)srow[sh] * K + scol[sh], As0 + ldso[sh]);
#pragma unroll
  for (int sh = 0; sh < 4; ++sh)
    gload_lds16(gB + (size_t)srow[sh] * K + scol[sh], Bs0 + ldso[sh]);
  __syncthreads();

  for (int k0 = 0; k0 < K; k0 += 64) {
    u16* const Ac = (k0 & 64) ? As1 : As0;
    u16* const Bc = (k0 & 64) ? Bs1 : Bs0;
    if (k0 + 64 < K) {
      u16* const An = (k0 & 64) ? As0 : As1;
      u16* const Bn = (k0 & 64) ? Bs0 : Bs1;
#pragma unroll
      for (int sh = 0; sh < 4; ++sh)
        gload_lds16(gA + (size_t)srow[sh] * K + k0 + 64 + scol[sh], An + ldso[sh]);
#pragma unroll
      for (int sh = 0; sh < 4; ++sh)
        gload_lds16(gB + (size_t)srow[sh] * K + k0 + 64 + scol[sh], Bn + ldso[sh]);
    }
#pragma unroll
    for (int kc = 0; kc < 2; ++kc) {
      bf16x8 af[4], bfv[4];
#pragma unroll
      for (int i = 0; i < 4; ++i) {
        const int ra = wr + i * 16 + l15;
        af[i] = *reinterpret_cast<const bf16x8*>(
            reinterpret_cast<const char*>(Ac) +
            ((ra * 128 + kc * 64 + lhi * 16) ^ ((ra & 7) << 4)));
        const int rb = wc + i * 16 + l15;
        bfv[i] = *reinterpret_cast<const bf16x8*>(
            reinterpret_cast<const char*>(Bc) +
            ((rb * 128 + kc * 64 + lhi * 16) ^ ((rb & 7) << 4)));
      }
#pragma unroll
      for (int mi = 0; mi < 4; ++mi)
#pragma unroll
        for (int ni = 0; ni < 4; ++ni)
          acc[mi][ni] = __builtin_amdgcn_mfma_f32_16x16x32_bf16(af[mi], bfv[ni], acc[mi][ni], 0, 0, 0);
    }
    __syncthreads();
  }
}

// ---------------------------------------------------------------------------
// Fused Q+K+V projection, one launch, 768 blocks.
// ---------------------------------------------------------------------------
__global__ __launch_bounds__(256) void gemm_qkv(
    const u16* __restrict__ A, const u16* __restrict__ Wq,
    const u16* __restrict__ Wk, const u16* __restrict__ Wv,
    u16* __restrict__ Qout, u16* __restrict__ Kout, u16* __restrict__ VTout,
    const float* __restrict__ cosb, const float* __restrict__ sinb)
{
  __shared__ u16 As[2][128 * 64];
  __shared__ u16 Bs[2][128 * 64];
  int lin = blockIdx.x;
  lin = (lin & 7) * 96 + (lin >> 3);          // XCD swizzle, nwg=768
  const int lane = threadIdx.x & 63, wvi = threadIdx.x >> 6;
  const int wr = (wvi >> 1) * 64, wc = (wvi & 1) * 64;
  const int l15 = lane & 15;
  f32x4 acc[4][4] = {};

  if (lin < 512) {
    const int row0 = (lin >> 4) * 128, col0 = (lin & 15) * 128;
    gemm_core_db(A, Wq, row0, col0, 2048, As[0], As[1], Bs[0], Bs[1], acc);
#pragma unroll
    for (int mi = 0; mi < 4; ++mi) {
      const int r0 = row0 + wr + mi * 16 + ((lane >> 4) << 2);
#pragma unroll
      for (int ni = 0; ni < 4; ++ni) {
        const int c = col0 + wc + ni * 16 + l15;
#pragma unroll
        for (int r = 0; r < 4; ++r) {
          const int s = (r0 + r) & 2047;
          const int jj = (c & 63) >> 1;
          const float cvv = cosb[s * 32 + jj], svv = sinb[s * 32 + jj];
          const float val = acc[mi][ni][r];
          const float part = __shfl_xor(val, 1);
          const float sgn = (c & 1) ? svv : -svv;
          Qout[(size_t)(r0 + r) * 2048 + c] = f2bf((val * cvv + part * sgn) * QSCL);
        }
      }
    }
  } else {
    const int t = lin - 512;
    const int bx = t & 7, by = t >> 3;
    const bool isV = bx >= 4;
    const int col0 = (bx & 3) * 128;
    const int row0 = by * 128;
    gemm_core_db(A, isV ? Wv : Wk, row0, col0, 2048, As[0], As[1], Bs[0], Bs[1], acc);
#pragma unroll
    for (int mi = 0; mi < 4; ++mi) {
      const int r0 = row0 + wr + mi * 16 + ((lane >> 4) << 2);
#pragma unroll
      for (int ni = 0; ni < 4; ++ni) {
        const int c = col0 + wc + ni * 16 + l15;
#pragma unroll
        for (int r = 0; r < 4; ++r) {
          if (isV) {
            VTout[(size_t)c * 4096 + (r0 + r)] = f2bf(acc[mi][ni][r]);
          } else {
            const int s = (r0 + r) & 2047;
            const int jj = (c & 63) >> 1;
            const float cvv = cosb[s * 32 + jj], svv = sinb[s * 32 + jj];
            const float val = acc[mi][ni][r];
            const float part = __shfl_xor(val, 1);
            const float sgn = (c & 1) ? svv : -svv;
            Kout[(size_t)(r0 + r) * 512 + c] = f2bf(val * cvv + part * sgn);
          }
        }
      }
    }
  }
}

// Output projection -> f32 d_out
__global__ __launch_bounds__(256) void gemm_out(
    const u16* __restrict__ A, const u16* __restrict__ Bw, float* __restrict__ C,
    int N, int K)
{
  __shared__ u16 As[2][128 * 64];
  __shared__ u16 Bs[2][128 * 64];
  const int nwg = gridDim.x * gridDim.y;
  int lin = blockIdx.y * gridDim.x + blockIdx.x;
  lin = (lin & 7) * (nwg >> 3) + (lin >> 3);
  const int row0 = (lin / gridDim.x) * 128, col0 = (lin % gridDim.x) * 128;
  f32x4 acc[4][4] = {};
  gemm_core_db(A, Bw, row0, col0, K, As[0], As[1], Bs[0], Bs[1], acc);

  const int lane = threadIdx.x & 63, wvi = threadIdx.x >> 6;
  const int wr = (wvi >> 1) * 64, wc = (wvi & 1) * 64;
  const int l15 = lane & 15;
#pragma unroll
  for (int mi = 0; mi < 4; ++mi) {
    const int r0 = row0 + wr + mi * 16 + ((lane >> 4) << 2);
#pragma unroll
    for (int ni = 0; ni < 4; ++ni) {
      const int c = col0 + wc + ni * 16 + l15;
#pragma unroll
      for (int r = 0; r < 4; ++r)
        C[(size_t)(r0 + r) * N + c] = acc[mi][ni][r];
    }
  }
}

// ---------------------------------------------------------------------------
// Attention LDS helpers: tiles [rows][64] bf16 (128B rows), byte ^= ((row&7)<<4)
// ---------------------------------------------------------------------------
__device__ __forceinline__ bf16x8 lds_read8(const u16* base, int row, int col) {
  const int byte = (row * 128 + col * 2) ^ ((row & 7) << 4);
  return *reinterpret_cast<const bf16x8*>(reinterpret_cast<const char*>(base) + byte);
}
__device__ __forceinline__ void lds_write4(u16* base, int row, int col, uint32_t v) {
  const int byte = (row * 128 + col * 2) ^ ((row & 7) << 4);
  *reinterpret_cast<uint32_t*>(reinterpret_cast<char*>(base) + byte) = v;
}

// ---------------------------------------------------------------------------
// One q-set (16 rows) update vs a 64-kv tile (R14-proven, VGPR 100).
// Swapped QK^T (lane l15 = q-row), exp2-domain, shfl-free defer-max,
// row-sum via ones-operand MFMA (lrun in C-layout), P relayout via LDS.
// ---------------------------------------------------------------------------
__device__ __forceinline__ void attn_set(
    const u16* __restrict__ Ks, const u16* __restrict__ Vt, u16* __restrict__ Plw,
    const bf16x8 qf[2], const bf16x8 ones, int t0, int qbase, int l15, int lhi,
    float& mrun, f32x4& lrun, f32x4 oacc[4])
{
  f32x4 s[4] = {};
  __builtin_amdgcn_s_setprio(1);
#pragma unroll
  for (int kc = 0; kc < 2; ++kc)
#pragma unroll
    for (int f = 0; f < 4; ++f) {
      const bf16x8 kf = lds_read8(Ks, f * 16 + l15, kc * 32 + lhi * 8);
      s[f] = __builtin_amdgcn_mfma_f32_16x16x32_bf16(kf, qf[kc], s[f], 0, 0, 0);
    }
  __builtin_amdgcn_s_setprio(0);
  float v[4][4];
#pragma unroll
  for (int f = 0; f < 4; ++f)
#pragma unroll
    for (int r = 0; r < 4; ++r) v[f][r] = s[f][r];
  if (t0 + 63 > qbase) {   // diagonal tile only (wave-uniform branch)
#pragma unroll
    for (int f = 0; f < 4; ++f)
#pragma unroll
      for (int r = 0; r < 4; ++r)
        if (t0 + f * 16 + lhi * 4 + r > qbase + l15) v[f][r] = -1e30f;
  }
  // fast path: exp first, in-lane max, scalar __all — no cross-lane shfl
  float p[4][4];
#pragma unroll
  for (int f = 0; f < 4; ++f)
#pragma unroll
    for (int r = 0; r < 4; ++r) p[f][r] = exp2x(v[f][r] - mrun);
  float m1 = max3f(p[0][0], p[0][1], p[0][2]);
  float m2 = max3f(p[0][3], p[1][0], p[1][1]);
  float m3 = max3f(p[1][2], p[1][3], p[2][0]);
  float m4 = max3f(p[2][1], p[2][2], p[2][3]);
  float m5 = max3f(p[3][0], p[3][1], p[3][2]);
  const float pmax = fmaxf(max3f(m1, m2, m3), max3f(m4, m5, p[3][3]));
  if (!__all(pmax <= 256.f)) {
    float t1 = max3f(v[0][0], v[0][1], v[0][2]);
    float t2 = max3f(v[0][3], v[1][0], v[1][1]);
    float t3 = max3f(v[1][2], v[1][3], v[2][0]);
    float t4 = max3f(v[2][1], v[2][2], v[2][3]);
    float t5 = max3f(v[3][0], v[3][1], v[3][2]);
    float mx = fmaxf(max3f(t1, t2, t3), max3f(t4, t5, v[3][3]));
    mx = fmaxf(mx, __shfl_xor(mx, 16));
    mx = fmaxf(mx, __shfl_xor(mx, 32));
    const float newm = fmaxf(mrun, mx);
    const float fac = exp2x(mrun - newm);
    mrun = newm;
    float facq[4];
#pragma unroll
    for (int r = 0; r < 4; ++r) facq[r] = __shfl(fac, lhi * 4 + r);
#pragma unroll
    for (int r = 0; r < 4; ++r) lrun[r] *= facq[r];
#pragma unroll
    for (int nf = 0; nf < 4; ++nf)
#pragma unroll
      for (int r = 0; r < 4; ++r) oacc[nf][r] *= facq[r];
#pragma unroll
    for (int f = 0; f < 4; ++f)
#pragma unroll
      for (int r = 0; r < 4; ++r) p[f][r] = exp2x(v[f][r] - mrun);
  }
#pragma unroll
  for (int f = 0; f < 4; ++f) {
    lds_write4(Plw, l15, f * 16 + lhi * 4,     pack2(p[f][0], p[f][1]));
    lds_write4(Plw, l15, f * 16 + lhi * 4 + 2, pack2(p[f][2], p[f][3]));
  }
  __builtin_amdgcn_s_setprio(1);
#pragma unroll
  for (int kc = 0; kc < 2; ++kc) {
    const bf16x8 pa = lds_read8(Plw, l15, kc * 32 + lhi * 8);
    lrun = __builtin_amdgcn_mfma_f32_16x16x32_bf16(pa, ones, lrun, 0, 0, 0);
#pragma unroll
    for (int nf = 0; nf < 4; ++nf) {
      const bf16x8 vf = lds_read8(Vt, nf * 16 + l15, kc * 32 + lhi * 8);
      oacc[nf] = __builtin_amdgcn_mfma_f32_16x16x32_bf16(pa, vf, oacc[nf], 0, 0, 0);
    }
  }
  __builtin_amdgcn_s_setprio(0);
}

__device__ __forceinline__ void attn_store(
    u16* __restrict__ O, const size_t qoff, const int h, const int qbase,
    const int l15, const int lhi, const f32x4 lrun, const f32x4 oacc[4])
{
  float linv[4];
#pragma unroll
  for (int r = 0; r < 4; ++r) linv[r] = 1.f / lrun[r];
#pragma unroll
  for (int nf = 0; nf < 4; ++nf)
#pragma unroll
    for (int r = 0; r < 4; ++r)
      O[qoff + (size_t)(qbase + lhi * 4 + r) * 2048 + h * 64 + nf * 16 + l15] =
          f2bf(oacc[nf][r] * linv[r]);
}

// ---------------------------------------------------------------------------
// Causal flash attention, GQA (R14-proven). Grid (16, 32, 2); 4 waves.
// Balanced pairing: block j handles q-tile j AND q-tile 31-j (33 updates).
// ---------------------------------------------------------------------------
__global__ __launch_bounds__(256) void attn_kernel(
    const u16* __restrict__ Q, const u16* __restrict__ K,
    const u16* __restrict__ VT, u16* __restrict__ O)
{
  __shared__ u16 Ks[2][64 * 64];
  __shared__ u16 Vt[2][64 * 64];
  __shared__ u16 Pl[4][16 * 64];

  const int j  = blockIdx.x;            // 0..15
  const int h  = blockIdx.y;
  const int b  = blockIdx.z;
  const int kh = h >> 2;
  const int tid = threadIdx.x, wv = tid >> 6, lane = tid & 63;
  const int l15 = lane & 15, lhi = lane >> 4;
  const size_t qoff = (size_t)b * 2048 * 2048;
  const size_t koff = (size_t)b * 2048 * 512;

  const int qAb = j * 64 + wv * 16;
  const int qBb = (31 - j) * 64 + wv * 16;

  const int idx0 = tid, idx1 = tid + 256;
  const int r0 = idx0 >> 3, u0 = (idx0 & 7) ^ (r0 & 7);
  const int r1 = idx1 >> 3, u1 = (idx1 & 7) ^ (r1 & 7);
  const u16* const kg0 = K + koff + (size_t)r0 * 512 + kh * 64 + u0 * 8;
  const u16* const kg1 = K + koff + (size_t)r1 * 512 + kh * 64 + u1 * 8;
  const u16* const vg0 = VT + (size_t)(kh * 64 + r0) * 4096 + b * 2048 + u0 * 8;
  const u16* const vg1 = VT + (size_t)(kh * 64 + r1) * 4096 + b * 2048 + u1 * 8;
  const int ld0 = wv * 512;
  const int ld1 = 2048 + wv * 512;

  bf16x8 qfA[2], qfB[2];
#pragma unroll
  for (int kc = 0; kc < 2; ++kc) {
    qfA[kc] = *reinterpret_cast<const bf16x8*>(
        Q + qoff + (size_t)(qAb + l15) * 2048 + h * 64 + kc * 32 + lhi * 8);
    qfB[kc] = *reinterpret_cast<const bf16x8*>(
        Q + qoff + (size_t)(qBb + l15) * 2048 + h * 64 + kc * 32 + lhi * 8);
  }
  bf16x8 ones;
#pragma unroll
  for (int i = 0; i < 8; ++i) ones[i] = (__bf16)1.0f;

  float mA = -1e30f, mB = -1e30f;
  f32x4 lA = {}, lB = {};
  f32x4 oA[4] = {}, oB[4] = {};

  const int tlast = 31 - j;

  gload_lds16(kg0, &Ks[0][ld0]);
  gload_lds16(kg1, &Ks[0][ld1]);
  gload_lds16(vg0, &Vt[0][ld0]);
  gload_lds16(vg1, &Vt[0][ld1]);
  __syncthreads();

  int cur = 0;
  for (int t = 0; t <= tlast; ++t) {
    const int t0 = t * 64;
    if (t < tlast) {
      const int n0 = t0 + 64;
      const int nb = cur ^ 1;
      gload_lds16(kg0 + (size_t)n0 * 512, &Ks[nb][ld0]);
      gload_lds16(kg1 + (size_t)n0 * 512, &Ks[nb][ld1]);
      gload_lds16(vg0 + n0, &Vt[nb][ld0]);
      gload_lds16(vg1 + n0, &Vt[nb][ld1]);
    }

    if (t <= j)
      attn_set(Ks[cur], Vt[cur], Pl[wv], qfA, ones, t0, qAb, l15, lhi, mA, lA, oA);
    attn_set(Ks[cur], Vt[cur], Pl[wv], qfB, ones, t0, qBb, l15, lhi, mB, lB, oB);

    __syncthreads();
    cur ^= 1;
  }

  attn_store(O, qoff, h, qAb, l15, lhi, lA, oA);
  attn_store(O, qoff, h, qBb, l15, lhi, lB, oB);
}

// ---------------------------------------------------------------------------
extern "C" void kernel_launch(void* const* d_in, const int* in_sizes, int n_in,
                              void* d_out, int out_size, void* d_ws, size_t ws_size,
                              hipStream_t stream)
{
  const float* x  = (const float*)d_in[0];
  const float* fc = (const float*)d_in[1];
  const float* fs = (const float*)d_in[2];
  // d_in[3] = mask (causal; analytic)
  const float* wq = (const float*)d_in[4];
  const float* wk = (const float*)d_in[5];
  const float* wv = (const float*)d_in[6];
  const float* wo = (const float*)d_in[7];
  float* out = (float*)d_out;

  u16* Xb  = (u16*)d_ws;                          // 4096 x 2048
  u16* Wqb = Xb  + (size_t)4096 * 2048;           // 2048 x 2048
  u16* Wkb = Wqb + (size_t)2048 * 2048;           // 512 x 2048
  u16* Wvb = Wkb + (size_t)512 * 2048;            // 512 x 2048
  u16* Qws = Wvb + (size_t)512 * 2048;            // 4096 x 2048
  u16* Kws = Qws + (size_t)4096 * 2048;           // 4096 x 512
  u16* VTws = Kws + (size_t)4096 * 512;           // 512 x 4096  (V transposed)
  u16* Wob = VTws + (size_t)512 * 4096;           // 2048 x 2048
  u16* Ows = Xb;                                  // alias: x dead after QKV

  dim3 blk(256);
  conv5<<<dim3(2359296 / 256), blk, 0, stream>>>(
      x, wq, wk, wv, wo, Xb, Wqb, Wkb, Wvb, Wob);
  // Fused Q+K+V projections (Q/K with RoPE; V transposed)
  gemm_qkv<<<dim3(768), blk, 0, stream>>>(Xb, Wqb, Wkb, Wvb, Qws, Kws, VTws, fc, fs);
  // Flash attention
  attn_kernel<<<dim3(16, 32, 2), blk, 0, stream>>>(Qws, Kws, VTws, Ows);
  // Output projection -> f32
  gemm_out<<<dim3(16, 32), blk, 0, stream>>>(Ows, Wob, out, 2048, 2048);
}